// Round 2
// baseline (1062.236 us; speedup 1.0000x reference)
//
#include <hip/hip_runtime.h>
#include <hip/hip_bf16.h>
#include <cstddef>

// Dtype finding (R1): inputs/outputs are FP32 (reference is jnp.float32; the
// observed threshold == 0.02*max|ref| with no bf16 floor applied). R0's NaN
// came from reinterpreting fp32 bits as bf16 (random exponents -> inf-inf).
//
// Pipeline (internal math bf16 MFMA, fp32 accum; ~2% error budget >> bf16 err):
//   0)   convert X, Wq..Wo fp32 -> bf16 in ws (biases stay fp32)
//   1-3) Q/K/V = Xb @ W{q,k,v}b^T + b   (gemm128_bt -> bf16)
//   4)   flash attention per (b,h,64-row q-tile) -> ctx bf16 (aliases Xb)
//   5)   out = ctx @ Wob^T + bo        (gemm128_bt -> fp32 d_out)

using bf16x8 = __attribute__((ext_vector_type(8))) short;   // 8 bf16 = 4 VGPRs
using f32x4  = __attribute__((ext_vector_type(4))) float;   // MFMA accum

#define MFMA16(a, b, c) __builtin_amdgcn_mfma_f32_16x16x32_bf16((a), (b), (c), 0, 0, 0)

static __device__ __forceinline__ bf16x8 zero8() {
    bf16x8 z;
#pragma unroll
    for (int i = 0; i < 8; ++i) z[i] = 0;
    return z;
}

// fp32 -> bf16, 8 elems/thread/iter, grid-stride. n8 = n/8 (all sizes %8==0).
__global__ __launch_bounds__(256) void cvt_f32_bf16(
    const float* __restrict__ in, __hip_bfloat16* __restrict__ out, int n8)
{
    int i = blockIdx.x * blockDim.x + threadIdx.x;
    const int stride = gridDim.x * blockDim.x;
    for (; i < n8; i += stride) {
        const float4* p = (const float4*)(in + (size_t)i * 8);
        float4 a = p[0], b = p[1];
        float f[8] = {a.x, a.y, a.z, a.w, b.x, b.y, b.z, b.w};
        bf16x8 o;
#pragma unroll
        for (int j = 0; j < 8; ++j) {
            __hip_bfloat16 h = __float2bfloat16(f[j]);
            o[j] = __builtin_bit_cast(short, h);
        }
        *(bf16x8*)(out + (size_t)i * 8) = o;
    }
}

// C[M,N] = A[M,K] @ W[N,K]^T + bias[N]; A,W bf16, bias fp32, C = OutT.
// 128x128 tile, BK=32, 4 waves in 2x2, each wave 64x64 via 4x4 MFMA 16x16x32.
// LDS rows padded 32->40 elems (start-bank period 8 -> only free 2-way alias).
template <typename OutT>
__global__ __launch_bounds__(256) void gemm128_bt(
    const __hip_bfloat16* __restrict__ A,
    const __hip_bfloat16* __restrict__ W,
    const float* __restrict__ bias,
    OutT* __restrict__ C,
    int M, int N, int K)
{
    __shared__ __hip_bfloat16 As[128][40];
    __shared__ __hip_bfloat16 Bs[128][40];

    const int tid  = threadIdx.x;
    const int lane = tid & 63;
    const int wave = tid >> 6;
    const int wm   = (wave >> 1) * 64;
    const int wn   = (wave & 1) * 64;
    const int quad = lane >> 4;
    const int low  = lane & 15;
    const int m0   = blockIdx.x * 128;
    const int n0   = blockIdx.y * 128;

    const int sr = tid >> 2;        // 0..63
    const int sc = (tid & 3) * 8;   // 0,8,16,24

    f32x4 acc[4][4] = {};

    for (int k0 = 0; k0 < K; k0 += 32) {
        const int ra0 = m0 + sr, ra1 = m0 + sr + 64;
        bf16x8 a0 = (ra0 < M) ? *(const bf16x8*)(A + (size_t)ra0 * K + k0 + sc) : zero8();
        bf16x8 a1 = (ra1 < M) ? *(const bf16x8*)(A + (size_t)ra1 * K + k0 + sc) : zero8();
        bf16x8 b0 = *(const bf16x8*)(W + (size_t)(n0 + sr)      * K + k0 + sc);
        bf16x8 b1 = *(const bf16x8*)(W + (size_t)(n0 + sr + 64) * K + k0 + sc);
        *(bf16x8*)&As[sr][sc]      = a0;
        *(bf16x8*)&As[sr + 64][sc] = a1;
        *(bf16x8*)&Bs[sr][sc]      = b0;
        *(bf16x8*)&Bs[sr + 64][sc] = b1;
        __syncthreads();

        bf16x8 af[4], bf[4];
#pragma unroll
        for (int i = 0; i < 4; ++i)
            af[i] = *(const bf16x8*)&As[wm + i * 16 + low][quad * 8];
#pragma unroll
        for (int j = 0; j < 4; ++j)
            bf[j] = *(const bf16x8*)&Bs[wn + j * 16 + low][quad * 8];
#pragma unroll
        for (int i = 0; i < 4; ++i)
#pragma unroll
            for (int j = 0; j < 4; ++j)
                acc[i][j] = MFMA16(af[i], bf[j], acc[i][j]);
        __syncthreads();
    }

    // epilogue: C/D layout col=lane&15, row=quad*4+reg (m89-verified)
#pragma unroll
    for (int j = 0; j < 4; ++j) {
        const int col = n0 + wn + j * 16 + low;
        const float bv = bias[col];
#pragma unroll
        for (int i = 0; i < 4; ++i) {
#pragma unroll
            for (int r = 0; r < 4; ++r) {
                const int row = m0 + wm + i * 16 + quad * 4 + r;
                if (row < M) {
                    const float v = acc[i][j][r] + bv;
                    if constexpr (__is_same(OutT, float))
                        C[(size_t)row * N + col] = v;
                    else
                        C[(size_t)row * N + col] = __float2bfloat16(v);
                }
            }
        }
    }
}

// Flash attention. Q/K/V/O layout: [B*S, 768], head h at cols h*64..h*64+63.
// Grid: (B*H, ceil(S/64)); block 256 = 4 waves, wave w owns q rows q0+w*16..+15.
#define SLEN   577
#define NHEAD  12
#define DMODEL 768

__global__ __launch_bounds__(256) void attn_kernel(
    const __hip_bfloat16* __restrict__ Q,
    const __hip_bfloat16* __restrict__ Kk,
    const __hip_bfloat16* __restrict__ V,
    __hip_bfloat16* __restrict__ O)
{
    const int bh   = blockIdx.x;
    const int b    = bh / NHEAD;
    const int h    = bh % NHEAD;
    const int q0   = blockIdx.y * 64;
    const int tid  = threadIdx.x;
    const int lane = tid & 63;
    const int wave = tid >> 6;
    const int quad = lane >> 4;
    const int low  = lane & 15;

    __shared__ __hip_bfloat16 Ks[32][72];      // keys x d, rows padded 64->72
    __shared__ __hip_bfloat16 Vt[64][40];      // d x keys, rows padded 32->40
    __shared__ __hip_bfloat16 Ps[4][16][40];   // per-wave P round-trip buffer

    const size_t base = (size_t)b * SLEN * DMODEL + (size_t)h * 64;

    // Q A-frags: A[m=lane&15][k=quad*8+j], two k-steps for Dh=64
    const int qrow = q0 + wave * 16 + low;
    bf16x8 qf0 = zero8(), qf1 = zero8();
    if (qrow < SLEN) {
        qf0 = *(const bf16x8*)(Q + base + (size_t)qrow * DMODEL + quad * 8);
        qf1 = *(const bf16x8*)(Q + base + (size_t)qrow * DMODEL + 32 + quad * 8);
    }

    f32x4 acc[4] = {};           // ctx accum, 4 d-tiles
    float m_run[4], l_run[4];
#pragma unroll
    for (int r = 0; r < 4; ++r) { m_run[r] = -1e30f; l_run[r] = 0.f; }

    const int skey = tid >> 3;        // 0..31
    const int sd   = (tid & 7) * 8;   // 0..56

    for (int c0 = 0; c0 < SLEN; c0 += 32) {
        __syncthreads();   // protect Ks/Vt from previous iteration's readers
        const int kg = c0 + skey;
        bf16x8 kv = zero8(), vv = zero8();
        if (kg < SLEN) {
            kv = *(const bf16x8*)(Kk + base + (size_t)kg * DMODEL + sd);
            vv = *(const bf16x8*)(V  + base + (size_t)kg * DMODEL + sd);
        }
        *(bf16x8*)&Ks[skey][sd] = kv;
#pragma unroll
        for (int j = 0; j < 8; ++j)          // transpose V into Vt
            Vt[sd + j][skey] = ((const __hip_bfloat16*)&vv)[j];
        __syncthreads();

        // S = Q K^T  (two 16-key n-tiles, Dh=64 = 2 MFMA k-steps)
        f32x4 st[2] = {};
#pragma unroll
        for (int t = 0; t < 2; ++t) {
            bf16x8 kf0 = *(const bf16x8*)&Ks[t * 16 + low][quad * 8];
            bf16x8 kf1 = *(const bf16x8*)&Ks[t * 16 + low][32 + quad * 8];
            st[t] = MFMA16(qf0, kf0, st[t]);
            st[t] = MFMA16(qf1, kf1, st[t]);
        }
#pragma unroll
        for (int t = 0; t < 2; ++t) {
            const bool valid = (c0 + t * 16 + low) < SLEN;
#pragma unroll
            for (int r = 0; r < 4; ++r) {
                const float s = st[t][r] * 0.125f;   // 1/sqrt(64)
                st[t][r] = valid ? s : -1e30f;
            }
        }
        // online softmax; C-layout: reg r is row quad*4+r, col low.
        // Row lives in lanes quad*16..quad*16+15 -> shfl_xor 1,2,4,8.
#pragma unroll
        for (int r = 0; r < 4; ++r) {
            float mx = fmaxf(st[0][r], st[1][r]);
#pragma unroll
            for (int off = 1; off < 16; off <<= 1)
                mx = fmaxf(mx, __shfl_xor(mx, off));
            const float mnew  = fmaxf(m_run[r], mx);
            const float alpha = __expf(m_run[r] - mnew);
            float p0 = __expf(st[0][r] - mnew);
            float p1 = __expf(st[1][r] - mnew);
            float ps = p0 + p1;
#pragma unroll
            for (int off = 1; off < 16; off <<= 1)
                ps += __shfl_xor(ps, off);
            l_run[r] = l_run[r] * alpha + ps;
            m_run[r] = mnew;
#pragma unroll
            for (int dt = 0; dt < 4; ++dt) acc[dt][r] *= alpha;
            Ps[wave][quad * 4 + r][low]      = __float2bfloat16(p0);
            Ps[wave][quad * 4 + r][16 + low] = __float2bfloat16(p1);
        }
        // PV: A-frag of P from per-wave LDS (same-wave DS ops are in-order)
        bf16x8 pf = *(const bf16x8*)&Ps[wave][low][quad * 8];
#pragma unroll
        for (int dt = 0; dt < 4; ++dt) {
            bf16x8 vf = *(const bf16x8*)&Vt[dt * 16 + low][quad * 8];
            acc[dt] = MFMA16(pf, vf, acc[dt]);
        }
    }

#pragma unroll
    for (int dt = 0; dt < 4; ++dt) {
        const int col = h * 64 + dt * 16 + low;
#pragma unroll
        for (int r = 0; r < 4; ++r) {
            const int row = q0 + wave * 16 + quad * 4 + r;
            if (row < SLEN)
                O[((size_t)b * SLEN + row) * DMODEL + col] =
                    __float2bfloat16(acc[dt][r] / l_run[r]);
        }
    }
}

extern "C" void kernel_launch(void* const* d_in, const int* in_sizes, int n_in,
                              void* d_out, int out_size, void* d_ws, size_t ws_size,
                              hipStream_t stream) {
    const float* X  = (const float*)d_in[0];
    const float* Wq = (const float*)d_in[1];
    const float* bq = (const float*)d_in[2];
    const float* Wk = (const float*)d_in[3];
    const float* bk = (const float*)d_in[4];
    const float* Wv = (const float*)d_in[5];
    const float* bv = (const float*)d_in[6];
    const float* Wo = (const float*)d_in[7];
    const float* bo = (const float*)d_in[8];

    const int Bb = 64, S = SLEN, D = DMODEL;
    const int M = Bb * S;                       // 36928
    const size_t szX = (size_t)M * D;           // 28,311,552
    const size_t szW = (size_t)D * D;           // 589,824

    // ws layout (bf16): Xb | Wqb | Wkb | Wvb | Wob | Qb | Kb | Vb ; ctx aliases Xb
    __hip_bfloat16* Xb  = (__hip_bfloat16*)d_ws;
    __hip_bfloat16* Wqb = Xb + szX;
    __hip_bfloat16* Wkb = Wqb + szW;
    __hip_bfloat16* Wvb = Wkb + szW;
    __hip_bfloat16* Wob = Wvb + szW;
    __hip_bfloat16* Qb  = Wob + szW;
    __hip_bfloat16* Kb  = Qb + szX;
    __hip_bfloat16* Vb  = Kb + szX;
    __hip_bfloat16* Cx  = Xb;                   // reuse after QKV gemms
    float* out = (float*)d_out;

    dim3 blk(256);
    cvt_f32_bf16<<<2048, blk, 0, stream>>>(X, Xb, (int)(szX / 8));
    cvt_f32_bf16<<<288,  blk, 0, stream>>>(Wq, Wqb, (int)(szW / 8));
    cvt_f32_bf16<<<288,  blk, 0, stream>>>(Wk, Wkb, (int)(szW / 8));
    cvt_f32_bf16<<<288,  blk, 0, stream>>>(Wv, Wvb, (int)(szW / 8));
    cvt_f32_bf16<<<288,  blk, 0, stream>>>(Wo, Wob, (int)(szW / 8));

    dim3 gG((M + 127) / 128, D / 128);          // 289 x 6
    gemm128_bt<__hip_bfloat16><<<gG, blk, 0, stream>>>(Xb, Wqb, bq, Qb, M, D, D);
    gemm128_bt<__hip_bfloat16><<<gG, blk, 0, stream>>>(Xb, Wkb, bk, Kb, M, D, D);
    gemm128_bt<__hip_bfloat16><<<gG, blk, 0, stream>>>(Xb, Wvb, bv, Vb, M, D, D);

    attn_kernel<<<dim3(Bb * NHEAD, (S + 63) / 64), blk, 0, stream>>>(Qb, Kb, Vb, Cx);

    gemm128_bt<float><<<gG, blk, 0, stream>>>(Cx, Wob, bo, out, M, D, D);
}